// Round 2
// baseline (149.930 us; speedup 1.0000x reference)
//
#include <hip/hip_runtime.h>

// ---------------- constants ----------------
constexpr int kH = 192, kW = 256, kHW = kH * kW;
constexpr int kFH = 48, kFW = 64, kFHW = kFH * kFW;
constexpr int kMH = 39, kMW = 51;
constexpr int kL = kMH * kMW;          // 1989
constexpr int kHeads = 32;
constexpr float kInitH = 256.0f / 5.0f; // init_h = W/INIT_SCALE
constexpr float kInitW = 192.0f / 5.0f; // init_w = H/INIT_SCALE
constexpr float kL2E = 1.44269504088896340736f;

struct HeadParams {
  int use;
  int ntop_c, nleft_c, nh_c, nw_c, dy1_c, dx1_c;   // ntop = new_top = max(top,0)
  int ntop_p, nleft_p, nh_p, nw_p, dy1_p, dx1_p;
  float h_c, w_c, h_p, w_p;
};

__device__ __forceinline__ float sigf(float x) { return 1.0f / (1.0f + __expf(-x)); }
__device__ __forceinline__ float stepH(int j) { return (float)(2 * abs(j - 19) + 1); }
__device__ __forceinline__ float stepW(int j) { return (float)(2 * abs(j - 25) + 1); }
__device__ __forceinline__ float dot4(float4 a, float4 b) {
  return fmaf(a.x, b.x, fmaf(a.y, b.y, fmaf(a.z, b.z, a.w * b.w)));
}

__device__ void headParams(int i, const int* clm, const int* plm, const float* sp, HeadParams& h) {
  int ccx = clm[2 * i], ccy = clm[2 * i + 1];
  int pcx = plm[2 * i], pcy = plm[2 * i + 1];
  h.use = !(((ccx == 0) && (ccy == 0)) || ((pcx == 0) && (pcy == 0)));
  {
    int top = ccy - (kMH + 1) / 2, bottom = ccy + kMH / 2;
    int left = ccx - (kMW + 1) / 2, right = ccx + kMW / 2;
    int dy1 = max(-top, 0), dy2 = max(bottom - kH, 0);
    int dx1 = max(-left, 0), dx2 = max(right - kW, 0);
    h.ntop_c = top + dy1; h.nleft_c = left + dx1; h.dy1_c = dy1; h.dx1_c = dx1;
    h.nh_c = max(kMH - dy1 - dy2, 0); h.nw_c = max(kMW - dx1 - dx2, 0);
  }
  {
    int top = pcy - (kMH + 1) / 2, bottom = pcy + kMH / 2;
    int left = pcx - (kMW + 1) / 2, right = pcx + kMW / 2;
    int dy1 = max(-top, 0), dy2 = max(bottom - kH, 0);
    int dx1 = max(-left, 0), dx2 = max(right - kW, 0);
    h.ntop_p = top + dy1; h.nleft_p = left + dx1; h.dy1_p = dy1; h.dx1_p = dx1;
    h.nh_p = max(kMH - dy1 - dy2, 0); h.nw_p = max(kMW - dx1 - dx2, 0);
  }
  float adj_cw = sp[4 * i + 0], adj_ch = sp[4 * i + 1];
  float adj_pw = sp[4 * i + 2], adj_ph = sp[4 * i + 3];
  h.h_c = kInitH * sigf(adj_ch);
  h.w_c = kInitW * sigf(adj_cw);
  h.h_p = kInitH * sigf(adj_ph);
  h.w_p = kInitW * sigf(adj_pw);
}

// -------- init output: flow = -1, mask = 0 --------
__global__ void k_init(float4* __restrict__ out, int n4, int nflow4) {
  int i = blockIdx.x * 256 + threadIdx.x;
  if (i < n4) {
    float v = (i < nflow4) ? -1.0f : 0.0f;
    out[i] = make_float4(v, v, v, v);
  }
}

// -------- quarter-res prelu + 1x1 conv (64 -> 4 ch) --------
__global__ void k_reduce(const float* __restrict__ fc, const float* __restrict__ fp,
                         const float* __restrict__ w1, const float* __restrict__ b1, const float* __restrict__ a1,
                         const float* __restrict__ w2, const float* __restrict__ b2, const float* __restrict__ a2,
                         float* __restrict__ fr) {
  int gid = blockIdx.x * 256 + threadIdx.x;
  if (gid >= 2 * kFHW) return;
  int which = gid / kFHW;          // block-uniform (kFHW = 3072 = 12*256)
  int pix = gid - which * kFHW;
  const float* f = which ? fp : fc;
  const float* w = which ? w2 : w1;
  const float* b = which ? b2 : b1;
  float a = which ? a2[0] : a1[0];
  float acc0 = 0.f, acc1 = 0.f, acc2 = 0.f, acc3 = 0.f;
  for (int c = 0; c < 64; ++c) {
    float x = f[c * kFHW + pix];
    float pr = fmaxf(x, 0.f) + a * fminf(x, 0.f);
    acc0 = fmaf(pr, w[c], acc0);
    acc1 = fmaf(pr, w[64 + c], acc1);
    acc2 = fmaf(pr, w[128 + c], acc2);
    acc3 = fmaf(pr, w[192 + c], acc3);
  }
  float* o = fr + which * 4 * kFHW;
  o[pix]            = acc0 + b[0];
  o[kFHW + pix]     = acc1 + b[1];
  o[2 * kFHW + pix] = acc2 + b[2];
  o[3 * kFHW + pix] = acc3 + b[3];
}

// -------- materialize K (cloth), V (location@cloth), P (person) patches --------
__global__ void k_patch(const float* __restrict__ fr, const float* __restrict__ loc,
                        const float* __restrict__ sp, const int* __restrict__ clm, const int* __restrict__ plm,
                        float4* __restrict__ Kall, float2* __restrict__ Vall, float4* __restrict__ Pall) {
  int i = blockIdx.y;
  int q = blockIdx.x * 256 + threadIdx.x;
  if (q >= kL) return;
  HeadParams hp; headParams(i, clm, plm, sp, hp);
  int qr = q / kMW, qc = q - qr * kMW;
  // c-side -> K, V   (rows = clip(new_top + r, 0, H-1): lower clip never active)
  {
    bool val = hp.use && (qr < hp.nh_c) && (qc < hp.nw_c);
    int row = min(hp.ntop_c + qr, kH - 1);
    int col = min(hp.nleft_c + qc, kW - 1);
    int mr = min(hp.dy1_c + qr, kMH - 1);
    int mc = min(hp.dx1_c + qc, kMW - 1);
    float mv = sigf((hp.h_c - stepH(mr)) * 2.f) * sigf((hp.w_c - stepW(mc)) * 2.f);
    int fpix = (row >> 2) * kFW + (col >> 2);
    float4 k; float2 v;
    if (val) {
      k.x = fr[fpix] * mv;
      k.y = fr[kFHW + fpix] * mv;
      k.z = fr[2 * kFHW + fpix] * mv;
      k.w = fr[3 * kFHW + fpix] * mv;
      v.x = loc[(2 * i) * kHW + row * kW + col];
      v.y = loc[(2 * i + 1) * kHW + row * kW + col];
    } else {
      k = make_float4(0.f, 0.f, 0.f, 0.f);
      v = make_float2(-1.f, -1.f);
    }
    Kall[i * kL + q] = k;
    Vall[i * kL + q] = v;
  }
  // p-side -> P
  {
    bool val = hp.use && (qr < hp.nh_p) && (qc < hp.nw_p);
    int row = min(hp.ntop_p + qr, kH - 1);
    int col = min(hp.nleft_p + qc, kW - 1);
    int mr = min(hp.dy1_p + qr, kMH - 1);
    int mc = min(hp.dx1_p + qc, kMW - 1);
    float mv = sigf((hp.h_p - stepH(mr)) * 2.f) * sigf((hp.w_p - stepW(mc)) * 2.f);
    int fpix = (row >> 2) * kFW + (col >> 2);
    float4 pv;
    if (val) {
      const float* frp = fr + 4 * kFHW;
      pv.x = frp[fpix] * mv;
      pv.y = frp[kFHW + fpix] * mv;
      pv.z = frp[2 * kFHW + fpix] * mv;
      pv.w = frp[3 * kFHW + fpix] * mv;
    } else {
      pv = make_float4(0.f, 0.f, 0.f, 0.f);
    }
    Pall[i * kL + q] = pv;
  }
}

// -------- two-pass partial softmax-attention over a q-range --------
__global__ void __launch_bounds__(256) k_attn(const float4* __restrict__ Kall, const float2* __restrict__ Vall,
                                              const float4* __restrict__ Pall, float4* __restrict__ part, int QS) {
  int i = blockIdx.z;
  int pch = blockIdx.x;
  int qsi = blockIdx.y;
  int p = pch * 249 + threadIdx.x;
  int pe = min(p, kL - 1);
  int qlen = (kL + QS - 1) / QS;
  int qs = qsi * qlen;
  int qe = min(qs + qlen, kL);
  const float4* Kp = Kall + i * kL;
  const float2* Vp = Vall + i * kL;
  float4 P = Pall[i * kL + pe];

  // pass 1: row max over [qs,qe)
  float m0 = -1e30f, m1 = -1e30f, m2 = -1e30f, m3 = -1e30f;
  int q = qs;
  for (; q + 4 <= qe; q += 4) {
    float4 k0 = Kp[q], k1 = Kp[q + 1], k2 = Kp[q + 2], k3 = Kp[q + 3];
    m0 = fmaxf(m0, dot4(P, k0));
    m1 = fmaxf(m1, dot4(P, k1));
    m2 = fmaxf(m2, dot4(P, k2));
    m3 = fmaxf(m3, dot4(P, k3));
  }
  for (; q < qe; ++q) m0 = fmaxf(m0, dot4(P, Kp[q]));
  float m = fmaxf(fmaxf(m0, m1), fmaxf(m2, m3));
  float mL = m * kL2E;

  // pass 2: exp-sum and weighted V sums
  float d0 = 0.f, d1 = 0.f, n00 = 0.f, n01 = 0.f, n10 = 0.f, n11 = 0.f;
  for (q = qs; q + 2 <= qe; q += 2) {
    float4 k0 = Kp[q], k1 = Kp[q + 1];
    float2 v0 = Vp[q], v1 = Vp[q + 1];
    float s0 = dot4(P, k0);
    float s1 = dot4(P, k1);
    float e0 = exp2f(fmaf(s0, kL2E, -mL));
    float e1 = exp2f(fmaf(s1, kL2E, -mL));
    d0 += e0; n00 = fmaf(e0, v0.x, n00); n01 = fmaf(e0, v0.y, n01);
    d1 += e1; n10 = fmaf(e1, v1.x, n10); n11 = fmaf(e1, v1.y, n11);
  }
  if (q < qe) {
    float4 k0 = Kp[q];
    float2 v0 = Vp[q];
    float e0 = exp2f(fmaf(dot4(P, k0), kL2E, -mL));
    d0 += e0; n00 = fmaf(e0, v0.x, n00); n01 = fmaf(e0, v0.y, n01);
  }
  part[(i * 2048 + pe) * QS + qsi] = make_float4(m, d0 + d1, n00 + n10, n01 + n11);
}

// -------- merge partials + scatter (no duplicates: valid rows/cols are unique) --------
__global__ void k_merge(const float4* __restrict__ part, int QS,
                        const float* __restrict__ sp, const int* __restrict__ clm, const int* __restrict__ plm,
                        float* __restrict__ out) {
  int i = blockIdx.y;
  int p = blockIdx.x * 256 + threadIdx.x;
  if (p >= kL) return;
  HeadParams hp; headParams(i, clm, plm, sp, hp);

  int pr = p / kMW, pc = p - pr * kMW;
  bool val = hp.use && (pr < hp.nh_p) && (pc < hp.nw_p);
  if (!val) return;

  const float4* pp = part + (i * 2048 + p) * QS;
  float M = -1e30f;
  for (int k = 0; k < QS; ++k) M = fmaxf(M, pp[k].x);
  float den = 0.f, n0 = 0.f, n1 = 0.f;
  for (int k = 0; k < QS; ++k) {
    float4 t = pp[k];
    float s = exp2f((t.x - M) * kL2E);
    den = fmaf(t.y, s, den);
    n0 = fmaf(t.z, s, n0);
    n1 = fmaf(t.w, s, n1);
  }
  float f0 = n0 / den, f1 = n1 / den;

  int R = hp.ntop_p + pr;   // <= H-1 guaranteed for valid pr
  int C = hp.nleft_p + pc;  // <= W-1 guaranteed for valid pc
  out[(2 * i) * kHW + R * kW + C] = f0;
  out[(2 * i + 1) * kHW + R * kW + C] = f1;
  out[64 * kHW + i * kHW + R * kW + C] = 1.0f;
}

extern "C" void kernel_launch(void* const* d_in, const int* in_sizes, int n_in,
                              void* d_out, int out_size, void* d_ws, size_t ws_size,
                              hipStream_t stream) {
  (void)in_sizes; (void)n_in;
  const float* loc = (const float*)d_in[0];
  const float* fc  = (const float*)d_in[1];
  const float* fp  = (const float*)d_in[2];
  const float* sp  = (const float*)d_in[3];
  const int* clm   = (const int*)d_in[6];
  const int* plm   = (const int*)d_in[7];
  const float* w1  = (const float*)d_in[8];
  const float* b1  = (const float*)d_in[9];
  const float* a1  = (const float*)d_in[10];
  const float* w2  = (const float*)d_in[11];
  const float* b2  = (const float*)d_in[12];
  const float* a2  = (const float*)d_in[13];
  float* out = (float*)d_out;
  char* ws = (char*)d_ws;

  // workspace layout (16B aligned)
  float*  fr   = (float*)(ws);                 // 2*4*3072 floats = 98304 B
  float4* Kall = (float4*)(ws + 98304);        // 32*1989*16 = 1018368 B
  float2* Vall = (float2*)(ws + 1116672);      // 32*1989*8  =  509184 B
  float4* Pall = (float4*)(ws + 1625856);      // 32*1989*16 = 1018368 B
  float4* part = (float4*)(ws + 2644224);      // 32*2048*QS*16 B

  size_t base = 2644224;
  size_t perQS = (size_t)32 * 2048 * 16;
  int QS = 1;
  if (ws_size >= base + 4 * perQS) QS = 4;
  else if (ws_size >= base + 2 * perQS) QS = 2;

  int n4 = out_size / 4;            // 1,179,648 (exactly divisible)
  int nflow4 = 64 * kHW / 4;        //   786,432
  k_init<<<(n4 + 255) / 256, 256, 0, stream>>>((float4*)out, n4, nflow4);
  k_reduce<<<(2 * kFHW + 255) / 256, 256, 0, stream>>>(fc, fp, w1, b1, a1, w2, b2, a2, fr);
  k_patch<<<dim3((kL + 255) / 256, kHeads), 256, 0, stream>>>(fr, loc, sp, clm, plm, Kall, Vall, Pall);
  k_attn<<<dim3(8, QS, kHeads), 256, 0, stream>>>(Kall, Vall, Pall, part, QS);
  k_merge<<<dim3((kL + 255) / 256, kHeads), 256, 0, stream>>>(part, QS, sp, clm, plm, out);
}

// Round 3
// 84.872 us; speedup vs baseline: 1.7665x; 1.7665x over previous
//
#include <hip/hip_runtime.h>

// ---------------- constants ----------------
constexpr int kH = 192, kW = 256, kHW = kH * kW;
constexpr int kFH = 48, kFW = 64, kFHW = kFH * kFW;
constexpr int kMH = 39, kMW = 51;
constexpr int kL = kMH * kMW;          // 1989
constexpr int kHeads = 32;
constexpr float kInitH = 256.0f / 5.0f; // init_h = W/INIT_SCALE
constexpr float kInitW = 192.0f / 5.0f; // init_w = H/INIT_SCALE
constexpr float kL2E = 1.44269504088896340736f;
constexpr float kBias = -16.0f;        // log2-domain bias (cancels in n/den)

struct HeadParams {
  int use;
  int ntop_c, nleft_c, nh_c, nw_c, dy1_c, dx1_c;   // ntop = new_top = max(top,0)
  int ntop_p, nleft_p, nh_p, nw_p, dy1_p, dx1_p;
  float h_c, w_c, h_p, w_p;
};

__device__ __forceinline__ float sigf(float x) { return 1.0f / (1.0f + __expf(-x)); }
__device__ __forceinline__ float stepH(int j) { return (float)(2 * abs(j - 19) + 1); }
__device__ __forceinline__ float stepW(int j) { return (float)(2 * abs(j - 25) + 1); }
__device__ __forceinline__ float dot4b(float4 a, float4 b, float bias) {
  return fmaf(a.x, b.x, fmaf(a.y, b.y, fmaf(a.z, b.z, fmaf(a.w, b.w, bias))));
}

__device__ void headParams(int i, const int* clm, const int* plm, const float* sp, HeadParams& h) {
  int ccx = clm[2 * i], ccy = clm[2 * i + 1];
  int pcx = plm[2 * i], pcy = plm[2 * i + 1];
  h.use = !(((ccx == 0) && (ccy == 0)) || ((pcx == 0) && (pcy == 0)));
  {
    int top = ccy - (kMH + 1) / 2, bottom = ccy + kMH / 2;
    int left = ccx - (kMW + 1) / 2, right = ccx + kMW / 2;
    int dy1 = max(-top, 0), dy2 = max(bottom - kH, 0);
    int dx1 = max(-left, 0), dx2 = max(right - kW, 0);
    h.ntop_c = top + dy1; h.nleft_c = left + dx1; h.dy1_c = dy1; h.dx1_c = dx1;
    h.nh_c = max(kMH - dy1 - dy2, 0); h.nw_c = max(kMW - dx1 - dx2, 0);
  }
  {
    int top = pcy - (kMH + 1) / 2, bottom = pcy + kMH / 2;
    int left = pcx - (kMW + 1) / 2, right = pcx + kMW / 2;
    int dy1 = max(-top, 0), dy2 = max(bottom - kH, 0);
    int dx1 = max(-left, 0), dx2 = max(right - kW, 0);
    h.ntop_p = top + dy1; h.nleft_p = left + dx1; h.dy1_p = dy1; h.dx1_p = dx1;
    h.nh_p = max(kMH - dy1 - dy2, 0); h.nw_p = max(kMW - dx1 - dx2, 0);
  }
  float adj_cw = sp[4 * i + 0], adj_ch = sp[4 * i + 1];
  float adj_pw = sp[4 * i + 2], adj_ph = sp[4 * i + 3];
  h.h_c = kInitH * sigf(adj_ch);
  h.w_c = kInitW * sigf(adj_cw);
  h.h_p = kInitH * sigf(adj_ph);
  h.w_p = kInitW * sigf(adj_pw);
}

// -------- init output: flow = -1, mask = 0 --------
__global__ void k_init(float4* __restrict__ out, int n4, int nflow4) {
  int i = blockIdx.x * 256 + threadIdx.x;
  if (i < n4) {
    float v = (i < nflow4) ? -1.0f : 0.0f;
    out[i] = make_float4(v, v, v, v);
  }
}

// -------- quarter-res prelu + 1x1 conv (64 -> 4 ch) --------
__global__ void k_reduce(const float* __restrict__ fc, const float* __restrict__ fp,
                         const float* __restrict__ w1, const float* __restrict__ b1, const float* __restrict__ a1,
                         const float* __restrict__ w2, const float* __restrict__ b2, const float* __restrict__ a2,
                         float* __restrict__ fr) {
  int gid = blockIdx.x * 256 + threadIdx.x;
  if (gid >= 2 * kFHW) return;
  int which = gid / kFHW;          // block-uniform (kFHW = 3072 = 12*256)
  int pix = gid - which * kFHW;
  const float* f = which ? fp : fc;
  const float* w = which ? w2 : w1;
  const float* b = which ? b2 : b1;
  float a = which ? a2[0] : a1[0];
  float acc0 = 0.f, acc1 = 0.f, acc2 = 0.f, acc3 = 0.f;
  for (int c = 0; c < 64; ++c) {
    float x = f[c * kFHW + pix];
    float pr = fmaxf(x, 0.f) + a * fminf(x, 0.f);
    acc0 = fmaf(pr, w[c], acc0);
    acc1 = fmaf(pr, w[64 + c], acc1);
    acc2 = fmaf(pr, w[128 + c], acc2);
    acc3 = fmaf(pr, w[192 + c], acc3);
  }
  float* o = fr + which * 4 * kFHW;
  o[pix]            = acc0 + b[0];
  o[kFHW + pix]     = acc1 + b[1];
  o[2 * kFHW + pix] = acc2 + b[2];
  o[3 * kFHW + pix] = acc3 + b[3];
}

// -------- materialize K (cloth), V (location@cloth), P (person, pre-scaled by log2e) --------
__global__ void k_patch(const float* __restrict__ fr, const float* __restrict__ loc,
                        const float* __restrict__ sp, const int* __restrict__ clm, const int* __restrict__ plm,
                        float4* __restrict__ Kall, float2* __restrict__ Vall, float4* __restrict__ Pall) {
  int i = blockIdx.y;
  int q = blockIdx.x * 256 + threadIdx.x;
  if (q >= kL) return;
  HeadParams hp; headParams(i, clm, plm, sp, hp);
  int qr = q / kMW, qc = q - qr * kMW;
  // c-side -> K, V   (rows = new_top + r, upper clip only for invalid lanes)
  {
    bool val = hp.use && (qr < hp.nh_c) && (qc < hp.nw_c);
    int row = min(hp.ntop_c + qr, kH - 1);
    int col = min(hp.nleft_c + qc, kW - 1);
    int mr = min(hp.dy1_c + qr, kMH - 1);
    int mc = min(hp.dx1_c + qc, kMW - 1);
    float mv = sigf((hp.h_c - stepH(mr)) * 2.f) * sigf((hp.w_c - stepW(mc)) * 2.f);
    int fpix = (row >> 2) * kFW + (col >> 2);
    float4 k; float2 v;
    if (val) {
      k.x = fr[fpix] * mv;
      k.y = fr[kFHW + fpix] * mv;
      k.z = fr[2 * kFHW + fpix] * mv;
      k.w = fr[3 * kFHW + fpix] * mv;
      v.x = loc[(2 * i) * kHW + row * kW + col];
      v.y = loc[(2 * i + 1) * kHW + row * kW + col];
    } else {
      k = make_float4(0.f, 0.f, 0.f, 0.f);
      v = make_float2(-1.f, -1.f);
    }
    Kall[i * kL + q] = k;
    Vall[i * kL + q] = v;
  }
  // p-side -> P (scaled by log2e so exp2 needs no extra multiply)
  {
    bool val = hp.use && (qr < hp.nh_p) && (qc < hp.nw_p);
    int row = min(hp.ntop_p + qr, kH - 1);
    int col = min(hp.nleft_p + qc, kW - 1);
    int mr = min(hp.dy1_p + qr, kMH - 1);
    int mc = min(hp.dx1_p + qc, kMW - 1);
    float mv = sigf((hp.h_p - stepH(mr)) * 2.f) * sigf((hp.w_p - stepW(mc)) * 2.f) * kL2E;
    int fpix = (row >> 2) * kFW + (col >> 2);
    float4 pv;
    if (val) {
      const float* frp = fr + 4 * kFHW;
      pv.x = frp[fpix] * mv;
      pv.y = frp[kFHW + fpix] * mv;
      pv.z = frp[2 * kFHW + fpix] * mv;
      pv.w = frp[3 * kFHW + fpix] * mv;
    } else {
      pv = make_float4(0.f, 0.f, 0.f, 0.f);
    }
    Pall[i * kL + q] = pv;
  }
}

// -------- single-pass partial softmax-attention over a q-range (no max pass) --------
__global__ void __launch_bounds__(256) k_attn(const float4* __restrict__ Kall, const float2* __restrict__ Vall,
                                              const float4* __restrict__ Pall, float4* __restrict__ part, int QS) {
  int i = blockIdx.z;
  int pch = blockIdx.x;
  int qsi = blockIdx.y;
  int p = pch * 249 + threadIdx.x;
  int pe = min(p, kL - 1);
  int qlen = (kL + QS - 1) / QS;
  int qs = qsi * qlen;
  int qe = min(qs + qlen, kL);
  const float4* Kp = Kall + i * kL;
  const float2* Vp = Vall + i * kL;
  float4 P = Pall[i * kL + pe];

  float d0 = 0.f, d1 = 0.f, d2 = 0.f, d3 = 0.f;
  float x0 = 0.f, x1 = 0.f, x2 = 0.f, x3 = 0.f;
  float y0 = 0.f, y1 = 0.f, y2 = 0.f, y3 = 0.f;
  int q = qs;
  for (; q + 4 <= qe; q += 4) {
    float4 k0 = Kp[q], k1 = Kp[q + 1], k2 = Kp[q + 2], k3 = Kp[q + 3];
    float2 v0 = Vp[q], v1 = Vp[q + 1], v2 = Vp[q + 2], v3 = Vp[q + 3];
    float e0 = exp2f(dot4b(P, k0, kBias));
    float e1 = exp2f(dot4b(P, k1, kBias));
    float e2 = exp2f(dot4b(P, k2, kBias));
    float e3 = exp2f(dot4b(P, k3, kBias));
    d0 += e0; x0 = fmaf(e0, v0.x, x0); y0 = fmaf(e0, v0.y, y0);
    d1 += e1; x1 = fmaf(e1, v1.x, x1); y1 = fmaf(e1, v1.y, y1);
    d2 += e2; x2 = fmaf(e2, v2.x, x2); y2 = fmaf(e2, v2.y, y2);
    d3 += e3; x3 = fmaf(e3, v3.x, x3); y3 = fmaf(e3, v3.y, y3);
  }
  for (; q < qe; ++q) {
    float4 k0 = Kp[q];
    float2 v0 = Vp[q];
    float e0 = exp2f(dot4b(P, k0, kBias));
    d0 += e0; x0 = fmaf(e0, v0.x, x0); y0 = fmaf(e0, v0.y, y0);
  }
  // layout [i][qsi][p] so writes (and merge reads) are lane-coalesced
  part[(i * QS + qsi) * 2048 + pe] = make_float4(d0 + d1 + d2 + d3, x0 + x1 + x2 + x3, y0 + y1 + y2 + y3, 0.f);
}

// -------- merge partials + scatter (valid (r,c) are unique: no duplicates) --------
__global__ void k_merge(const float4* __restrict__ part, int QS,
                        const float* __restrict__ sp, const int* __restrict__ clm, const int* __restrict__ plm,
                        float* __restrict__ out) {
  int i = blockIdx.y;
  int p = blockIdx.x * 256 + threadIdx.x;
  if (p >= kL) return;
  HeadParams hp; headParams(i, clm, plm, sp, hp);

  int pr = p / kMW, pc = p - pr * kMW;
  bool val = hp.use && (pr < hp.nh_p) && (pc < hp.nw_p);
  if (!val) return;

  const float4* pp = part + i * QS * 2048 + p;
  float den = 0.f, n0 = 0.f, n1 = 0.f;
  for (int k = 0; k < QS; ++k) {
    float4 t = pp[k * 2048];
    den += t.x; n0 += t.y; n1 += t.z;
  }
  float inv = 1.0f / den;
  float f0 = n0 * inv, f1 = n1 * inv;

  int R = hp.ntop_p + pr;   // <= H-1 guaranteed for valid pr
  int C = hp.nleft_p + pc;  // <= W-1 guaranteed for valid pc
  out[(2 * i) * kHW + R * kW + C] = f0;
  out[(2 * i + 1) * kHW + R * kW + C] = f1;
  out[64 * kHW + i * kHW + R * kW + C] = 1.0f;
}

extern "C" void kernel_launch(void* const* d_in, const int* in_sizes, int n_in,
                              void* d_out, int out_size, void* d_ws, size_t ws_size,
                              hipStream_t stream) {
  (void)in_sizes; (void)n_in;
  const float* loc = (const float*)d_in[0];
  const float* fc  = (const float*)d_in[1];
  const float* fp  = (const float*)d_in[2];
  const float* sp  = (const float*)d_in[3];
  const int* clm   = (const int*)d_in[6];
  const int* plm   = (const int*)d_in[7];
  const float* w1  = (const float*)d_in[8];
  const float* b1  = (const float*)d_in[9];
  const float* a1  = (const float*)d_in[10];
  const float* w2  = (const float*)d_in[11];
  const float* b2  = (const float*)d_in[12];
  const float* a2  = (const float*)d_in[13];
  float* out = (float*)d_out;
  char* ws = (char*)d_ws;

  // workspace layout (16B aligned)
  float*  fr   = (float*)(ws);                 // 2*4*3072 floats = 98304 B
  float4* Kall = (float4*)(ws + 98304);        // 32*1989*16 = 1018368 B
  float2* Vall = (float2*)(ws + 1116672);      // 32*1989*8  =  509184 B
  float4* Pall = (float4*)(ws + 1625856);      // 32*1989*16 = 1018368 B
  float4* part = (float4*)(ws + 2644224);      // 32*QS*2048*16 B

  size_t base = 2644224;
  size_t perQS = (size_t)32 * 2048 * 16;       // 1 MiB per q-split
  int QS = 1;
  if (ws_size >= base + 16 * perQS) QS = 16;
  else if (ws_size >= base + 8 * perQS) QS = 8;
  else if (ws_size >= base + 4 * perQS) QS = 4;
  else if (ws_size >= base + 2 * perQS) QS = 2;

  int n4 = out_size / 4;            // 1,179,648 (exactly divisible)
  int nflow4 = 64 * kHW / 4;        //   786,432
  k_init<<<(n4 + 255) / 256, 256, 0, stream>>>((float4*)out, n4, nflow4);
  k_reduce<<<(2 * kFHW + 255) / 256, 256, 0, stream>>>(fc, fp, w1, b1, a1, w2, b2, a2, fr);
  k_patch<<<dim3((kL + 255) / 256, kHeads), 256, 0, stream>>>(fr, loc, sp, clm, plm, Kall, Vall, Pall);
  k_attn<<<dim3(8, QS, kHeads), 256, 0, stream>>>(Kall, Vall, Pall, part, QS);
  k_merge<<<dim3((kL + 255) / 256, kHeads), 256, 0, stream>>>(part, QS, sp, clm, plm, out);
}

// Round 4
// 76.169 us; speedup vs baseline: 1.9684x; 1.1143x over previous
//
#include <hip/hip_runtime.h>

// ---------------- constants ----------------
constexpr int kH = 192, kW = 256, kHW = kH * kW;
constexpr int kFH = 48, kFW = 64, kFHW = kFH * kFW;
constexpr int kMH = 39, kMW = 51;
constexpr int kL = kMH * kMW;          // 1989
constexpr int kHeads = 32;
constexpr float kInitH = 256.0f / 5.0f; // init_h = W/INIT_SCALE
constexpr float kInitW = 192.0f / 5.0f; // init_w = H/INIT_SCALE
constexpr float kL2E = 1.44269504088896340736f;
constexpr float kBias = -16.0f;        // log2-domain bias (cancels in n/den)

// raw hardware exp2: our args are in [-40, 0] — no denormal/range fixup needed.
__device__ __forceinline__ float fast_exp2(float x) {
#if __has_builtin(__builtin_amdgcn_exp2f)
  return __builtin_amdgcn_exp2f(x);
#else
  float r;
  // s_nop 1 covers the TRANS->VALU wait-state hazard (asm is opaque to the
  // compiler's hazard recognizer).
  asm("v_exp_f32 %0, %1\n\ts_nop 1" : "=v"(r) : "v"(x));
  return r;
#endif
}

struct HeadParams {
  int use;
  int ntop_c, nleft_c, nh_c, nw_c, dy1_c, dx1_c;   // ntop = new_top = max(top,0)
  int ntop_p, nleft_p, nh_p, nw_p, dy1_p, dx1_p;
  float h_c, w_c, h_p, w_p;
};

__device__ __forceinline__ float sigf(float x) { return 1.0f / (1.0f + __expf(-x)); }
__device__ __forceinline__ float stepH(int j) { return (float)(2 * abs(j - 19) + 1); }
__device__ __forceinline__ float stepW(int j) { return (float)(2 * abs(j - 25) + 1); }
__device__ __forceinline__ float dot4b(float4 a, float4 b, float bias) {
  return fmaf(a.x, b.x, fmaf(a.y, b.y, fmaf(a.z, b.z, fmaf(a.w, b.w, bias))));
}

__device__ void headParams(int i, const int* clm, const int* plm, const float* sp, HeadParams& h) {
  int ccx = clm[2 * i], ccy = clm[2 * i + 1];
  int pcx = plm[2 * i], pcy = plm[2 * i + 1];
  h.use = !(((ccx == 0) && (ccy == 0)) || ((pcx == 0) && (pcy == 0)));
  {
    int top = ccy - (kMH + 1) / 2, bottom = ccy + kMH / 2;
    int left = ccx - (kMW + 1) / 2, right = ccx + kMW / 2;
    int dy1 = max(-top, 0), dy2 = max(bottom - kH, 0);
    int dx1 = max(-left, 0), dx2 = max(right - kW, 0);
    h.ntop_c = top + dy1; h.nleft_c = left + dx1; h.dy1_c = dy1; h.dx1_c = dx1;
    h.nh_c = max(kMH - dy1 - dy2, 0); h.nw_c = max(kMW - dx1 - dx2, 0);
  }
  {
    int top = pcy - (kMH + 1) / 2, bottom = pcy + kMH / 2;
    int left = pcx - (kMW + 1) / 2, right = pcx + kMW / 2;
    int dy1 = max(-top, 0), dy2 = max(bottom - kH, 0);
    int dx1 = max(-left, 0), dx2 = max(right - kW, 0);
    h.ntop_p = top + dy1; h.nleft_p = left + dx1; h.dy1_p = dy1; h.dx1_p = dx1;
    h.nh_p = max(kMH - dy1 - dy2, 0); h.nw_p = max(kMW - dx1 - dx2, 0);
  }
  float adj_cw = sp[4 * i + 0], adj_ch = sp[4 * i + 1];
  float adj_pw = sp[4 * i + 2], adj_ph = sp[4 * i + 3];
  h.h_c = kInitH * sigf(adj_ch);
  h.w_c = kInitW * sigf(adj_cw);
  h.h_p = kInitH * sigf(adj_ph);
  h.w_p = kInitW * sigf(adj_pw);
}

// -------- init output: flow = -1, mask = 0 --------
__global__ void k_init(float4* __restrict__ out, int n4, int nflow4) {
  int i = blockIdx.x * 256 + threadIdx.x;
  if (i < n4) {
    float v = (i < nflow4) ? -1.0f : 0.0f;
    out[i] = make_float4(v, v, v, v);
  }
}

// -------- quarter-res prelu + 1x1 conv (64 -> 4 ch) --------
__global__ void k_reduce(const float* __restrict__ fc, const float* __restrict__ fp,
                         const float* __restrict__ w1, const float* __restrict__ b1, const float* __restrict__ a1,
                         const float* __restrict__ w2, const float* __restrict__ b2, const float* __restrict__ a2,
                         float* __restrict__ fr) {
  int gid = blockIdx.x * 256 + threadIdx.x;
  if (gid >= 2 * kFHW) return;
  int which = gid / kFHW;          // block-uniform (kFHW = 3072 = 12*256)
  int pix = gid - which * kFHW;
  const float* f = which ? fp : fc;
  const float* w = which ? w2 : w1;
  const float* b = which ? b2 : b1;
  float a = which ? a2[0] : a1[0];
  float acc0 = 0.f, acc1 = 0.f, acc2 = 0.f, acc3 = 0.f;
  for (int c = 0; c < 64; ++c) {
    float x = f[c * kFHW + pix];
    float pr = fmaxf(x, 0.f) + a * fminf(x, 0.f);
    acc0 = fmaf(pr, w[c], acc0);
    acc1 = fmaf(pr, w[64 + c], acc1);
    acc2 = fmaf(pr, w[128 + c], acc2);
    acc3 = fmaf(pr, w[192 + c], acc3);
  }
  float* o = fr + which * 4 * kFHW;
  o[pix]            = acc0 + b[0];
  o[kFHW + pix]     = acc1 + b[1];
  o[2 * kFHW + pix] = acc2 + b[2];
  o[3 * kFHW + pix] = acc3 + b[3];
}

// -------- materialize K (cloth), V (location@cloth), P (person, pre-scaled by log2e) --------
__global__ void k_patch(const float* __restrict__ fr, const float* __restrict__ loc,
                        const float* __restrict__ sp, const int* __restrict__ clm, const int* __restrict__ plm,
                        float4* __restrict__ Kall, float2* __restrict__ Vall, float4* __restrict__ Pall) {
  int i = blockIdx.y;
  int q = blockIdx.x * 256 + threadIdx.x;
  if (q >= kL) return;
  HeadParams hp; headParams(i, clm, plm, sp, hp);
  int qr = q / kMW, qc = q - qr * kMW;
  // c-side -> K, V   (rows = new_top + r, upper clip only for invalid lanes)
  {
    bool val = hp.use && (qr < hp.nh_c) && (qc < hp.nw_c);
    int row = min(hp.ntop_c + qr, kH - 1);
    int col = min(hp.nleft_c + qc, kW - 1);
    int mr = min(hp.dy1_c + qr, kMH - 1);
    int mc = min(hp.dx1_c + qc, kMW - 1);
    float mv = sigf((hp.h_c - stepH(mr)) * 2.f) * sigf((hp.w_c - stepW(mc)) * 2.f);
    int fpix = (row >> 2) * kFW + (col >> 2);
    float4 k; float2 v;
    if (val) {
      k.x = fr[fpix] * mv;
      k.y = fr[kFHW + fpix] * mv;
      k.z = fr[2 * kFHW + fpix] * mv;
      k.w = fr[3 * kFHW + fpix] * mv;
      v.x = loc[(2 * i) * kHW + row * kW + col];
      v.y = loc[(2 * i + 1) * kHW + row * kW + col];
    } else {
      k = make_float4(0.f, 0.f, 0.f, 0.f);
      v = make_float2(-1.f, -1.f);
    }
    Kall[i * kL + q] = k;
    Vall[i * kL + q] = v;
  }
  // p-side -> P (scaled by log2e so exp2 needs no extra multiply)
  {
    bool val = hp.use && (qr < hp.nh_p) && (qc < hp.nw_p);
    int row = min(hp.ntop_p + qr, kH - 1);
    int col = min(hp.nleft_p + qc, kW - 1);
    int mr = min(hp.dy1_p + qr, kMH - 1);
    int mc = min(hp.dx1_p + qc, kMW - 1);
    float mv = sigf((hp.h_p - stepH(mr)) * 2.f) * sigf((hp.w_p - stepW(mc)) * 2.f) * kL2E;
    int fpix = (row >> 2) * kFW + (col >> 2);
    float4 pv;
    if (val) {
      const float* frp = fr + 4 * kFHW;
      pv.x = frp[fpix] * mv;
      pv.y = frp[kFHW + fpix] * mv;
      pv.z = frp[2 * kFHW + fpix] * mv;
      pv.w = frp[3 * kFHW + fpix] * mv;
    } else {
      pv = make_float4(0.f, 0.f, 0.f, 0.f);
    }
    Pall[i * kL + q] = pv;
  }
}

// -------- single-pass partial softmax-attention over a q-range (no max pass) --------
__global__ void __launch_bounds__(256) k_attn(const float4* __restrict__ Kall, const float2* __restrict__ Vall,
                                              const float4* __restrict__ Pall, float4* __restrict__ part, int QS) {
  int i = blockIdx.z;
  int pch = blockIdx.x;
  int qsi = blockIdx.y;
  int p = pch * 249 + threadIdx.x;
  int pe = min(p, kL - 1);
  int qlen = (kL + QS - 1) / QS;
  int qs = qsi * qlen;
  int qe = min(qs + qlen, kL);
  const float4* Kp = Kall + i * kL;
  const float2* Vp = Vall + i * kL;
  float4 P = Pall[i * kL + pe];

  float d0 = 0.f, d1 = 0.f, d2 = 0.f, d3 = 0.f;
  float x0 = 0.f, x1 = 0.f, x2 = 0.f, x3 = 0.f;
  float y0 = 0.f, y1 = 0.f, y2 = 0.f, y3 = 0.f;
  int q = qs;
  for (; q + 4 <= qe; q += 4) {
    float4 k0 = Kp[q], k1 = Kp[q + 1], k2 = Kp[q + 2], k3 = Kp[q + 3];
    float2 v0 = Vp[q], v1 = Vp[q + 1], v2 = Vp[q + 2], v3 = Vp[q + 3];
    float e0 = fast_exp2(dot4b(P, k0, kBias));
    float e1 = fast_exp2(dot4b(P, k1, kBias));
    float e2 = fast_exp2(dot4b(P, k2, kBias));
    float e3 = fast_exp2(dot4b(P, k3, kBias));
    d0 += e0; x0 = fmaf(e0, v0.x, x0); y0 = fmaf(e0, v0.y, y0);
    d1 += e1; x1 = fmaf(e1, v1.x, x1); y1 = fmaf(e1, v1.y, y1);
    d2 += e2; x2 = fmaf(e2, v2.x, x2); y2 = fmaf(e2, v2.y, y2);
    d3 += e3; x3 = fmaf(e3, v3.x, x3); y3 = fmaf(e3, v3.y, y3);
  }
  for (; q < qe; ++q) {
    float4 k0 = Kp[q];
    float2 v0 = Vp[q];
    float e0 = fast_exp2(dot4b(P, k0, kBias));
    d0 += e0; x0 = fmaf(e0, v0.x, x0); y0 = fmaf(e0, v0.y, y0);
  }
  // layout [i][qsi][p] so writes (and merge reads) are lane-coalesced
  part[(i * QS + qsi) * 2048 + pe] = make_float4(d0 + d1 + d2 + d3, x0 + x1 + x2 + x3, y0 + y1 + y2 + y3, 0.f);
}

// -------- merge partials + scatter (valid (r,c) are unique: no duplicates) --------
__global__ void k_merge(const float4* __restrict__ part, int QS,
                        const float* __restrict__ sp, const int* __restrict__ clm, const int* __restrict__ plm,
                        float* __restrict__ out) {
  int i = blockIdx.y;
  int p = blockIdx.x * 256 + threadIdx.x;
  if (p >= kL) return;
  HeadParams hp; headParams(i, clm, plm, sp, hp);

  int pr = p / kMW, pc = p - pr * kMW;
  bool val = hp.use && (pr < hp.nh_p) && (pc < hp.nw_p);
  if (!val) return;

  const float4* pp = part + i * QS * 2048 + p;
  float den = 0.f, n0 = 0.f, n1 = 0.f;
  for (int k = 0; k < QS; ++k) {
    float4 t = pp[k * 2048];
    den += t.x; n0 += t.y; n1 += t.z;
  }
  float inv = 1.0f / den;
  float f0 = n0 * inv, f1 = n1 * inv;

  int R = hp.ntop_p + pr;   // <= H-1 guaranteed for valid pr
  int C = hp.nleft_p + pc;  // <= W-1 guaranteed for valid pc
  out[(2 * i) * kHW + R * kW + C] = f0;
  out[(2 * i + 1) * kHW + R * kW + C] = f1;
  out[64 * kHW + i * kHW + R * kW + C] = 1.0f;
}

extern "C" void kernel_launch(void* const* d_in, const int* in_sizes, int n_in,
                              void* d_out, int out_size, void* d_ws, size_t ws_size,
                              hipStream_t stream) {
  (void)in_sizes; (void)n_in;
  const float* loc = (const float*)d_in[0];
  const float* fc  = (const float*)d_in[1];
  const float* fp  = (const float*)d_in[2];
  const float* sp  = (const float*)d_in[3];
  const int* clm   = (const int*)d_in[6];
  const int* plm   = (const int*)d_in[7];
  const float* w1  = (const float*)d_in[8];
  const float* b1  = (const float*)d_in[9];
  const float* a1  = (const float*)d_in[10];
  const float* w2  = (const float*)d_in[11];
  const float* b2  = (const float*)d_in[12];
  const float* a2  = (const float*)d_in[13];
  float* out = (float*)d_out;
  char* ws = (char*)d_ws;

  // workspace layout (16B aligned)
  float*  fr   = (float*)(ws);                 // 2*4*3072 floats = 98304 B
  float4* Kall = (float4*)(ws + 98304);        // 32*1989*16 = 1018368 B
  float2* Vall = (float2*)(ws + 1116672);      // 32*1989*8  =  509184 B
  float4* Pall = (float4*)(ws + 1625856);      // 32*1989*16 = 1018368 B
  float4* part = (float4*)(ws + 2644224);      // 32*QS*2048*16 B

  size_t base = 2644224;
  size_t perQS = (size_t)32 * 2048 * 16;       // 1 MiB per q-split
  int QS = 1;
  if (ws_size >= base + 16 * perQS) QS = 16;
  else if (ws_size >= base + 8 * perQS) QS = 8;
  else if (ws_size >= base + 4 * perQS) QS = 4;
  else if (ws_size >= base + 2 * perQS) QS = 2;

  int n4 = out_size / 4;            // 1,179,648 (exactly divisible)
  int nflow4 = 64 * kHW / 4;        //   786,432
  k_init<<<(n4 + 255) / 256, 256, 0, stream>>>((float4*)out, n4, nflow4);
  k_reduce<<<(2 * kFHW + 255) / 256, 256, 0, stream>>>(fc, fp, w1, b1, a1, w2, b2, a2, fr);
  k_patch<<<dim3((kL + 255) / 256, kHeads), 256, 0, stream>>>(fr, loc, sp, clm, plm, Kall, Vall, Pall);
  k_attn<<<dim3(8, QS, kHeads), 256, 0, stream>>>(Kall, Vall, Pall, part, QS);
  k_merge<<<dim3((kL + 255) / 256, kHeads), 256, 0, stream>>>(part, QS, sp, clm, plm, out);
}

// Round 5
// 59.834 us; speedup vs baseline: 2.5058x; 1.2730x over previous
//
#include <hip/hip_runtime.h>

// ---------------- constants ----------------
constexpr int kH = 192, kW = 256, kHW = kH * kW;
constexpr int kFH = 48, kFW = 64, kFHW = kFH * kFW;
constexpr int kMH = 39, kMW = 51;
constexpr int kL = kMH * kMW;          // 1989
constexpr int kLP = 2048;              // padded q length
constexpr int kHeads = 32;
constexpr float kInitH = 256.0f / 5.0f; // init_h = W/INIT_SCALE
constexpr float kInitW = 192.0f / 5.0f; // init_w = H/INIT_SCALE
constexpr float kL2E = 1.44269504088896340736f;
constexpr float kBias = -16.0f;        // log2-domain bias (cancels in n/den)
// pad q (kL..kLP): K=0 -> e = 2^kBias exactly; V=(-1,-1). Analytic removal:
constexpr float kPadCorr = 59.0f / 65536.0f;   // 59 * 2^-16, exact in fp32

typedef float v2f __attribute__((ext_vector_type(2)));
__device__ __forceinline__ v2f pkfma(v2f a, v2f b, v2f c) {
  return __builtin_elementwise_fma(a, b, c);
}

// raw hardware exp2: args in [-40, 0] — no denormal/range fixup needed.
__device__ __forceinline__ float fast_exp2(float x) {
#if __has_builtin(__builtin_amdgcn_exp2f)
  return __builtin_amdgcn_exp2f(x);
#else
  float r;
  asm("v_exp_f32 %0, %1\n\ts_nop 1" : "=v"(r) : "v"(x));
  return r;
#endif
}

struct HeadParams {
  int use;
  int ntop_c, nleft_c, nh_c, nw_c, dy1_c, dx1_c;   // ntop = new_top = max(top,0)
  int ntop_p, nleft_p, nh_p, nw_p, dy1_p, dx1_p;
  float h_c, w_c, h_p, w_p;
};

__device__ __forceinline__ float sigf(float x) { return 1.0f / (1.0f + __expf(-x)); }
__device__ __forceinline__ float stepH(int j) { return (float)(2 * abs(j - 19) + 1); }
__device__ __forceinline__ float stepW(int j) { return (float)(2 * abs(j - 25) + 1); }

__device__ void headParams(int i, const int* clm, const int* plm, const float* sp, HeadParams& h) {
  int ccx = clm[2 * i], ccy = clm[2 * i + 1];
  int pcx = plm[2 * i], pcy = plm[2 * i + 1];
  h.use = !(((ccx == 0) && (ccy == 0)) || ((pcx == 0) && (pcy == 0)));
  {
    int top = ccy - (kMH + 1) / 2, bottom = ccy + kMH / 2;
    int left = ccx - (kMW + 1) / 2, right = ccx + kMW / 2;
    int dy1 = max(-top, 0), dy2 = max(bottom - kH, 0);
    int dx1 = max(-left, 0), dx2 = max(right - kW, 0);
    h.ntop_c = top + dy1; h.nleft_c = left + dx1; h.dy1_c = dy1; h.dx1_c = dx1;
    h.nh_c = max(kMH - dy1 - dy2, 0); h.nw_c = max(kMW - dx1 - dx2, 0);
  }
  {
    int top = pcy - (kMH + 1) / 2, bottom = pcy + kMH / 2;
    int left = pcx - (kMW + 1) / 2, right = pcx + kMW / 2;
    int dy1 = max(-top, 0), dy2 = max(bottom - kH, 0);
    int dx1 = max(-left, 0), dx2 = max(right - kW, 0);
    h.ntop_p = top + dy1; h.nleft_p = left + dx1; h.dy1_p = dy1; h.dx1_p = dx1;
    h.nh_p = max(kMH - dy1 - dy2, 0); h.nw_p = max(kMW - dx1 - dx2, 0);
  }
  float adj_cw = sp[4 * i + 0], adj_ch = sp[4 * i + 1];
  float adj_pw = sp[4 * i + 2], adj_ph = sp[4 * i + 3];
  h.h_c = kInitH * sigf(adj_ch);
  h.w_c = kInitW * sigf(adj_cw);
  h.h_p = kInitH * sigf(adj_ph);
  h.w_p = kInitW * sigf(adj_pw);
}

// -------- init output: flow = -1, mask = 0 --------
__global__ void k_init(float4* __restrict__ out, int n4, int nflow4) {
  int i = blockIdx.x * 256 + threadIdx.x;
  if (i < n4) {
    float v = (i < nflow4) ? -1.0f : 0.0f;
    out[i] = make_float4(v, v, v, v);
  }
}

// -------- quarter-res prelu + 1x1 conv (64 -> 4 ch) --------
__global__ void k_reduce(const float* __restrict__ fc, const float* __restrict__ fp,
                         const float* __restrict__ w1, const float* __restrict__ b1, const float* __restrict__ a1,
                         const float* __restrict__ w2, const float* __restrict__ b2, const float* __restrict__ a2,
                         float* __restrict__ fr) {
  int gid = blockIdx.x * 256 + threadIdx.x;
  if (gid >= 2 * kFHW) return;
  int which = gid / kFHW;          // block-uniform (kFHW = 3072 = 12*256)
  int pix = gid - which * kFHW;
  const float* f = which ? fp : fc;
  const float* w = which ? w2 : w1;
  const float* b = which ? b2 : b1;
  float a = which ? a2[0] : a1[0];
  float acc0 = 0.f, acc1 = 0.f, acc2 = 0.f, acc3 = 0.f;
  for (int c = 0; c < 64; ++c) {
    float x = f[c * kFHW + pix];
    float pr = fmaxf(x, 0.f) + a * fminf(x, 0.f);
    acc0 = fmaf(pr, w[c], acc0);
    acc1 = fmaf(pr, w[64 + c], acc1);
    acc2 = fmaf(pr, w[128 + c], acc2);
    acc3 = fmaf(pr, w[192 + c], acc3);
  }
  float* o = fr + which * 4 * kFHW;
  o[pix]            = acc0 + b[0];
  o[kFHW + pix]     = acc1 + b[1];
  o[2 * kFHW + pix] = acc2 + b[2];
  o[3 * kFHW + pix] = acc3 + b[3];
}

// -------- materialize planar K (cloth), V (location@cloth), P (person, pre-scaled) --------
// K planes: Kpl[c][i][q] c=0..3, plane stride 32*2048. V planes: Vpl[d][i][q] d=0..1.
__global__ void k_patch(const float* __restrict__ fr, const float* __restrict__ loc,
                        const float* __restrict__ sp, const int* __restrict__ clm, const int* __restrict__ plm,
                        float* __restrict__ Kpl, float* __restrict__ Vpl, float4* __restrict__ Pall) {
  int i = blockIdx.y;
  int q = blockIdx.x * 256 + threadIdx.x;   // q in [0, 2048)
  HeadParams hp; headParams(i, clm, plm, sp, hp);
  int qr = q / kMW, qc = q - qr * kMW;
  constexpr int PS = kHeads * kLP;          // plane stride
  int o = i * kLP + q;
  // c-side -> K, V (pad q >= kL: K=0, V=-1, corrected analytically in merge)
  {
    bool val = (q < kL) && hp.use && (qr < hp.nh_c) && (qc < hp.nw_c);
    int row = min(hp.ntop_c + qr, kH - 1);
    int col = min(hp.nleft_c + qc, kW - 1);
    int mr = min(hp.dy1_c + qr, kMH - 1);
    int mc = min(hp.dx1_c + qc, kMW - 1);
    float mv = sigf((hp.h_c - stepH(mr)) * 2.f) * sigf((hp.w_c - stepW(mc)) * 2.f);
    int fpix = (row >> 2) * kFW + (col >> 2);
    float kx = 0.f, ky = 0.f, kz = 0.f, kw = 0.f, vx = -1.f, vy = -1.f;
    if (val) {
      kx = fr[fpix] * mv;
      ky = fr[kFHW + fpix] * mv;
      kz = fr[2 * kFHW + fpix] * mv;
      kw = fr[3 * kFHW + fpix] * mv;
      vx = loc[(2 * i) * kHW + row * kW + col];
      vy = loc[(2 * i + 1) * kHW + row * kW + col];
    }
    Kpl[o] = kx; Kpl[PS + o] = ky; Kpl[2 * PS + o] = kz; Kpl[3 * PS + o] = kw;
    Vpl[o] = vx; Vpl[PS + o] = vy;
  }
  // p-side -> P (scaled by log2e so exp2 needs no extra multiply)
  if (q < kL) {
    bool val = hp.use && (qr < hp.nh_p) && (qc < hp.nw_p);
    int row = min(hp.ntop_p + qr, kH - 1);
    int col = min(hp.nleft_p + qc, kW - 1);
    int mr = min(hp.dy1_p + qr, kMH - 1);
    int mc = min(hp.dx1_p + qc, kMW - 1);
    float mv = sigf((hp.h_p - stepH(mr)) * 2.f) * sigf((hp.w_p - stepW(mc)) * 2.f) * kL2E;
    int fpix = (row >> 2) * kFW + (col >> 2);
    float4 pv = make_float4(0.f, 0.f, 0.f, 0.f);
    if (val) {
      const float* frp = fr + 4 * kFHW;
      pv.x = frp[fpix] * mv;
      pv.y = frp[kFHW + fpix] * mv;
      pv.z = frp[2 * kFHW + fpix] * mv;
      pv.w = frp[3 * kFHW + fpix] * mv;
    }
    Pall[i * kL + q] = pv;
  }
}

// -------- single-pass partial softmax-attention, packed fp32, static trip count --------
template<int QLEN>
__global__ void __launch_bounds__(256) k_attn_t(const float* __restrict__ Kpl, const float* __restrict__ Vpl,
                                                const float4* __restrict__ Pall,
                                                float* __restrict__ pD, float* __restrict__ pX,
                                                float* __restrict__ pY) {
  constexpr int PS = kHeads * kLP;
  int i = blockIdx.z;
  int qsi = blockIdx.y;
  int p = blockIdx.x * 249 + threadIdx.x;
  int pe = min(p, kL - 1);
  const int base = i * kLP + qsi * QLEN;
  const float* kx = Kpl + base;
  const float* ky = Kpl + PS + base;
  const float* kz = Kpl + 2 * PS + base;
  const float* kw = Kpl + 3 * PS + base;
  const float* vx = Vpl + base;
  const float* vy = Vpl + PS + base;
  float4 P = Pall[i * kL + pe];
  v2f PX = {P.x, P.x}, PY = {P.y, P.y}, PZ = {P.z, P.z}, PW = {P.w, P.w};
  const v2f B = {kBias, kBias};
  v2f dA = {0.f, 0.f}, dB = {0.f, 0.f};
  v2f xA = {0.f, 0.f}, xB = {0.f, 0.f};
  v2f yA = {0.f, 0.f}, yB = {0.f, 0.f};
#pragma unroll 8
  for (int t = 0; t < QLEN; t += 4) {
    // pair A: q = t, t+1
    v2f sA = pkfma(PW, *(const v2f*)(kw + t), B);
    sA = pkfma(PZ, *(const v2f*)(kz + t), sA);
    sA = pkfma(PY, *(const v2f*)(ky + t), sA);
    sA = pkfma(PX, *(const v2f*)(kx + t), sA);
    // pair B: q = t+2, t+3
    v2f sB = pkfma(PW, *(const v2f*)(kw + t + 2), B);
    sB = pkfma(PZ, *(const v2f*)(kz + t + 2), sB);
    sB = pkfma(PY, *(const v2f*)(ky + t + 2), sB);
    sB = pkfma(PX, *(const v2f*)(kx + t + 2), sB);
    v2f eA = {fast_exp2(sA.x), fast_exp2(sA.y)};
    v2f eB = {fast_exp2(sB.x), fast_exp2(sB.y)};
    dA += eA;
    xA = pkfma(eA, *(const v2f*)(vx + t), xA);
    yA = pkfma(eA, *(const v2f*)(vy + t), yA);
    dB += eB;
    xB = pkfma(eB, *(const v2f*)(vx + t + 2), xB);
    yB = pkfma(eB, *(const v2f*)(vy + t + 2), yB);
  }
  int o = (i * gridDim.y + qsi) * kLP + pe;
  pD[o] = dA.x + dA.y + dB.x + dB.y;
  pX[o] = xA.x + xA.y + xB.x + xB.y;
  pY[o] = yA.x + yA.y + yB.x + yB.y;
}

// -------- merge partials + pad correction + scatter (valid (r,c) unique) --------
__global__ void k_merge(const float* __restrict__ pD, const float* __restrict__ pX, const float* __restrict__ pY,
                        int QS,
                        const float* __restrict__ sp, const int* __restrict__ clm, const int* __restrict__ plm,
                        float* __restrict__ out) {
  int i = blockIdx.y;
  int p = blockIdx.x * 256 + threadIdx.x;
  if (p >= kL) return;
  HeadParams hp; headParams(i, clm, plm, sp, hp);

  int pr = p / kMW, pc = p - pr * kMW;
  bool val = hp.use && (pr < hp.nh_p) && (pc < hp.nw_p);
  if (!val) return;

  float den = -kPadCorr, n0 = kPadCorr, n1 = kPadCorr;  // remove pad-q contribution
  for (int k = 0; k < QS; ++k) {
    int o = (i * QS + k) * kLP + p;
    den += pD[o]; n0 += pX[o]; n1 += pY[o];
  }
  float inv = 1.0f / den;
  float f0 = n0 * inv, f1 = n1 * inv;

  int R = hp.ntop_p + pr;   // <= H-1 guaranteed for valid pr
  int C = hp.nleft_p + pc;  // <= W-1 guaranteed for valid pc
  out[(2 * i) * kHW + R * kW + C] = f0;
  out[(2 * i + 1) * kHW + R * kW + C] = f1;
  out[64 * kHW + i * kHW + R * kW + C] = 1.0f;
}

extern "C" void kernel_launch(void* const* d_in, const int* in_sizes, int n_in,
                              void* d_out, int out_size, void* d_ws, size_t ws_size,
                              hipStream_t stream) {
  (void)in_sizes; (void)n_in;
  const float* loc = (const float*)d_in[0];
  const float* fc  = (const float*)d_in[1];
  const float* fp  = (const float*)d_in[2];
  const float* sp  = (const float*)d_in[3];
  const int* clm   = (const int*)d_in[6];
  const int* plm   = (const int*)d_in[7];
  const float* w1  = (const float*)d_in[8];
  const float* b1  = (const float*)d_in[9];
  const float* a1  = (const float*)d_in[10];
  const float* w2  = (const float*)d_in[11];
  const float* b2  = (const float*)d_in[12];
  const float* a2  = (const float*)d_in[13];
  float* out = (float*)d_out;
  char* ws = (char*)d_ws;

  // workspace layout (16B aligned)
  float*  fr   = (float*)(ws);                 // 98,304 B
  float*  Kpl  = (float*)(ws + 98304);         // 4*32*2048*4 = 1,048,576 B
  float*  Vpl  = (float*)(ws + 1146880);       // 2*32*2048*4 =   524,288 B
  float4* Pall = (float4*)(ws + 1671168);      // 32*1989*16  = 1,018,368 B
  size_t base = 2689536;
  size_t perQS = (size_t)3 * kHeads * kLP * 4; // 786,432 B per q-slice (3 planes)
  int QS = 1;
  if (ws_size >= base + 16 * perQS) QS = 16;
  else if (ws_size >= base + 8 * perQS) QS = 8;
  else if (ws_size >= base + 4 * perQS) QS = 4;
  else if (ws_size >= base + 2 * perQS) QS = 2;
  float* pD = (float*)(ws + base);
  float* pX = pD + (size_t)QS * kHeads * kLP;
  float* pY = pX + (size_t)QS * kHeads * kLP;

  int n4 = out_size / 4;            // 1,179,648 (exactly divisible)
  int nflow4 = 64 * kHW / 4;        //   786,432
  k_init<<<(n4 + 255) / 256, 256, 0, stream>>>((float4*)out, n4, nflow4);
  k_reduce<<<(2 * kFHW + 255) / 256, 256, 0, stream>>>(fc, fp, w1, b1, a1, w2, b2, a2, fr);
  k_patch<<<dim3(kLP / 256, kHeads), 256, 0, stream>>>(fr, loc, sp, clm, plm, Kpl, Vpl, Pall);
  dim3 ag(8, QS, kHeads);
  switch (QS) {
    case 16: k_attn_t<128><<<ag, 256, 0, stream>>>(Kpl, Vpl, Pall, pD, pX, pY); break;
    case 8:  k_attn_t<256><<<ag, 256, 0, stream>>>(Kpl, Vpl, Pall, pD, pX, pY); break;
    case 4:  k_attn_t<512><<<ag, 256, 0, stream>>>(Kpl, Vpl, Pall, pD, pX, pY); break;
    case 2:  k_attn_t<1024><<<ag, 256, 0, stream>>>(Kpl, Vpl, Pall, pD, pX, pY); break;
    default: k_attn_t<2048><<<ag, 256, 0, stream>>>(Kpl, Vpl, Pall, pD, pX, pY); break;
  }
  k_merge<<<dim3((kL + 255) / 256, kHeads), 256, 0, stream>>>(pD, pX, pY, QS, sp, clm, plm, out);
}